// Round 2
// baseline (1098.312 us; speedup 1.0000x reference)
//
#include <hip/hip_runtime.h>

// ---------------------------------------------------------------------------
// Problem: B=8, R=128, H=W=4096
//   C    = alpha*I + 2*gamma * N @ N^T        [128x128], SPD -> Cinv symmetric
//   out  = 2*gamma * (Ak_L @ N^T) @ Cinv      (uses Cinv symmetry!)
// Pipeline (3 launches):
//   k_gram  : Gpart[b][ks] = partial N*N^T (bf16 MFMA) + writes Nbf = bf16(N)
//   k_aninv : blocks 0..7   -> per-batch Gauss-Jordan inverse (fp32, 256 thr)
//             blocks 8..519 -> AN = A(fp32->bf16) @ Nbf^T  (the 512MB stream)
//             Inversion rides free under the memory-bound GEMM: 52.2KB LDS +
//             launch_bounds(256,3) => 3 blocks/CU => all 520 blocks resident.
//   k_final : out = 2g * AN @ Cinv, fp32 VALU (Cinv staged fp32 in LDS; no
//             bf16 rounding in stage 2 -> strictly fewer roundings than the
//             old Mt path).
// ---------------------------------------------------------------------------

typedef __attribute__((ext_vector_type(8))) short bf16x8;
typedef __attribute__((ext_vector_type(4))) float f32x4;
typedef __attribute__((ext_vector_type(4))) unsigned int u32x4;

#define MFMA16(a, b, c) __builtin_amdgcn_mfma_f32_16x16x32_bf16((a), (b), (c), 0, 0, 0)
#define NSPLIT 8
#define PAD 68  // shorts; 136B row stride -> 2-bank shift/row, 2-way worst (free)

__device__ __forceinline__ unsigned short f2bf(float f) {
  union { float f; unsigned u; } v; v.f = f;
  unsigned u = v.u;
  return (unsigned short)((u + 0x7FFFu + ((u >> 16) & 1u)) >> 16);  // RNE
}
__device__ __forceinline__ unsigned pack2(float x, float y) {
  return (unsigned)f2bf(x) | ((unsigned)f2bf(y) << 16);
}
__device__ __forceinline__ float sel8row(const float* ar, int s) {  // ar[s], s runtime 0..7
  return (s & 4) ? ((s & 2) ? ((s & 1) ? ar[7] : ar[6]) : ((s & 1) ? ar[5] : ar[4]))
                 : ((s & 2) ? ((s & 1) ? ar[3] : ar[2]) : ((s & 1) ? ar[1] : ar[0]));
}

// ---------------------------------------------------------------------------
// Kernel 1: Gram partials + Nbf cast. grid (NSPLIT=8, 8 batch), 256 thr.
// Gpart[b][ks][128][128] fp32 = N[:, ks*512:+512] @ same^T  (bf16 MFMA)
// Nbf[b][r][w] bf16 = bf16(N) -- written from the already-packed tiles.
// ---------------------------------------------------------------------------
__global__ __launch_bounds__(256) void k_gram(const float* __restrict__ N,
                                              float* __restrict__ Gpart,
                                              unsigned short* __restrict__ Nbf) {
  __attribute__((aligned(16))) __shared__ unsigned short lds[128 * 72];
  int ks = blockIdx.x, b = blockIdx.y;
  const float* Nb = N + (size_t)b * 524288 + ks * 512;
  int t = threadIdx.x;
  int wave = t >> 6, lane = t & 63, quad = lane >> 4, l16 = lane & 15;
  f32x4 acc[2][8];
#pragma unroll
  for (int i = 0; i < 2; i++)
#pragma unroll
    for (int j = 0; j < 8; j++) acc[i][j] = (f32x4){0.f, 0.f, 0.f, 0.f};
  int srow = t >> 1, shalf = t & 1;
  const float* srcb = Nb + (size_t)srow * 4096 + shalf * 32;
  unsigned short* dptr = lds + srow * 72 + shalf * 32;
  unsigned short* nbb = Nbf + (size_t)b * 524288 + (size_t)srow * 4096 + ks * 512 + shalf * 32;
  for (int it = 0; it < 8; ++it) {
    u32x4 pk0, pk1;
    {
      f32x4 v0 = *(const f32x4*)(srcb + it * 64 + 0);
      f32x4 v1 = *(const f32x4*)(srcb + it * 64 + 4);
      f32x4 v2 = *(const f32x4*)(srcb + it * 64 + 8);
      f32x4 v3 = *(const f32x4*)(srcb + it * 64 + 12);
      pk0[0] = pack2(v0[0], v0[1]); pk0[1] = pack2(v0[2], v0[3]);
      pk0[2] = pack2(v1[0], v1[1]); pk0[3] = pack2(v1[2], v1[3]);
      pk1[0] = pack2(v2[0], v2[1]); pk1[1] = pack2(v2[2], v2[3]);
      pk1[2] = pack2(v3[0], v3[1]); pk1[3] = pack2(v3[2], v3[3]);
    }
    u32x4 pk2, pk3;
    {
      f32x4 v0 = *(const f32x4*)(srcb + it * 64 + 16);
      f32x4 v1 = *(const f32x4*)(srcb + it * 64 + 20);
      f32x4 v2 = *(const f32x4*)(srcb + it * 64 + 24);
      f32x4 v3 = *(const f32x4*)(srcb + it * 64 + 28);
      pk2[0] = pack2(v0[0], v0[1]); pk2[1] = pack2(v0[2], v0[3]);
      pk2[2] = pack2(v1[0], v1[1]); pk2[3] = pack2(v1[2], v1[3]);
      pk3[0] = pack2(v2[0], v2[1]); pk3[1] = pack2(v2[2], v2[3]);
      pk3[2] = pack2(v3[0], v3[1]); pk3[3] = pack2(v3[2], v3[3]);
    }
    // bf16 copy of N (row-major), reused by k_aninv as the B operand
    *(u32x4*)(nbb + it * 64 + 0) = pk0;
    *(u32x4*)(nbb + it * 64 + 8) = pk1;
    *(u32x4*)(nbb + it * 64 + 16) = pk2;
    *(u32x4*)(nbb + it * 64 + 24) = pk3;
    __syncthreads();
    *(u32x4*)(dptr + 0) = pk0;
    *(u32x4*)(dptr + 8) = pk1;
    *(u32x4*)(dptr + 16) = pk2;
    *(u32x4*)(dptr + 24) = pk3;
    __syncthreads();
    bf16x8 af[2][2], bfv[8][2];
#pragma unroll
    for (int mt = 0; mt < 2; mt++)
#pragma unroll
      for (int kk = 0; kk < 2; kk++)
        af[mt][kk] = *(const bf16x8*)(lds + (wave * 32 + mt * 16 + l16) * 72 + (kk * 4 + quad) * 8);
#pragma unroll
    for (int nt = 0; nt < 8; nt++)
#pragma unroll
      for (int kk = 0; kk < 2; kk++)
        bfv[nt][kk] = *(const bf16x8*)(lds + (nt * 16 + l16) * 72 + (kk * 4 + quad) * 8);
#pragma unroll
    for (int mt = 0; mt < 2; mt++)
#pragma unroll
      for (int nt = 0; nt < 8; nt++)
#pragma unroll
        for (int kk = 0; kk < 2; kk++)
          acc[mt][nt] = MFMA16(af[mt][kk], bfv[nt][kk], acc[mt][nt]);
  }
  float* Gp = Gpart + ((size_t)(b * NSPLIT + ks) << 14);
#pragma unroll
  for (int mt = 0; mt < 2; mt++)
#pragma unroll
    for (int nt = 0; nt < 8; nt++)
#pragma unroll
      for (int rg = 0; rg < 4; rg++) {
        int row = wave * 32 + mt * 16 + quad * 4 + rg;
        int col = nt * 16 + l16;
        Gp[row * 128 + col] = acc[mt][nt][rg];
      }
}

// ---------------------------------------------------------------------------
// Kernel 2: fused AN-GEMM + inversion. grid 520 blocks, 256 thr.
//  blk 0..7   : Gauss-Jordan inverse of C = alpha*I + 2g*sum(Gpart), batch=blk
//  blk 8..519 : AN[b][h][r] = sum_w A[h][w]*Nbf[r][w]; b=blk&7 (XCD swizzle),
//               mtile=(blk>>3)-1. 64(h)x128(r) tile, BK=64.
//  Pipeline: A 2-deep reg prefetch (HBM), B 1-deep (L2-hot), LDS dbuf,
//  one raw s_barrier/iter, lgkmcnt(0)-only before it (no vmcnt drain).
// ---------------------------------------------------------------------------
__device__ __forceinline__ void an_step(
    f32x4& A0, f32x4& A1, f32x4& A2, f32x4& A3,
    u32x4& B0, u32x4& B1, u32x4& B2, u32x4& B3,
    unsigned short* adst, unsigned short* bdst,
    const unsigned short* lap, const unsigned short* lbp,
    const float* asrc, const unsigned short* bsrc,
    int it, int wm, int wr, int quad, int l16,
    f32x4 (&acc)[2][4]) {
  u32x4 pa0, pa1;  // pack A fp32->bf16 (vmcnt wait lands here, counted)
  pa0[0] = pack2(A0[0], A0[1]); pa0[1] = pack2(A0[2], A0[3]);
  pa0[2] = pack2(A1[0], A1[1]); pa0[3] = pack2(A1[2], A1[3]);
  pa1[0] = pack2(A2[0], A2[1]); pa1[1] = pack2(A2[2], A2[3]);
  pa1[2] = pack2(A3[0], A3[1]); pa1[3] = pack2(A3[2], A3[3]);
  *(u32x4*)(adst + 0) = pa0;
  *(u32x4*)(adst + 8) = pa1;
  *(u32x4*)(bdst + 0) = B0;
  *(u32x4*)(bdst + 8) = B1;
  *(u32x4*)(bdst + 16) = B2;
  *(u32x4*)(bdst + 24) = B3;
  asm volatile("s_waitcnt lgkmcnt(0)" ::: "memory");  // LDS visible; vmcnt untouched
  __builtin_amdgcn_s_barrier();
  __builtin_amdgcn_sched_barrier(0);
  if (it + 1 < 64) {  // B prefetch for it+1 (issue first: stays oldest)
    int kb = (it + 1) * 64;
    B0 = *(const u32x4*)(bsrc + kb + 0);
    B1 = *(const u32x4*)(bsrc + kb + 8);
    B2 = *(const u32x4*)(bsrc + kb + 16);
    B3 = *(const u32x4*)(bsrc + kb + 24);
  }
  if (it + 2 < 64) {  // A prefetch for it+2 into this register set
    int ka = (it + 2) * 64;
    A0 = *(const f32x4*)(asrc + ka + 0);
    A1 = *(const f32x4*)(asrc + ka + 4);
    A2 = *(const f32x4*)(asrc + ka + 8);
    A3 = *(const f32x4*)(asrc + ka + 12);
  }
  __builtin_amdgcn_sched_barrier(0);
  bf16x8 af[2][2], bfv[4][2];
#pragma unroll
  for (int mt = 0; mt < 2; mt++)
#pragma unroll
    for (int kk = 0; kk < 2; kk++)
      af[mt][kk] = *(const bf16x8*)(lap + (wm * 32 + mt * 16 + l16) * PAD + (kk * 4 + quad) * 8);
#pragma unroll
  for (int rt = 0; rt < 4; rt++)
#pragma unroll
    for (int kk = 0; kk < 2; kk++)
      bfv[rt][kk] = *(const bf16x8*)(lbp + (wr * 64 + rt * 16 + l16) * PAD + (kk * 4 + quad) * 8);
#pragma unroll
  for (int mt = 0; mt < 2; mt++)
#pragma unroll
    for (int rt = 0; rt < 4; rt++)
#pragma unroll
      for (int kk = 0; kk < 2; kk++)
        acc[mt][rt] = MFMA16(af[mt][kk], bfv[rt][kk], acc[mt][rt]);
}

__global__ __launch_bounds__(256, 3) void k_aninv(
    const float* __restrict__ A, const unsigned short* __restrict__ Nbf,
    const float* __restrict__ Gpart, const float* __restrict__ alpha,
    const float* __restrict__ gamma, float* __restrict__ ANf,
    float* __restrict__ Cinv) {
  // union'd LDS: AN path uses all 52224B; inv path overlays 2KB at the front
  __attribute__((aligned(16))) __shared__ unsigned short smem[2 * 64 * PAD + 2 * 128 * PAD];
  int blk = blockIdx.x;
  int t = threadIdx.x;
  if (blk < 8) {
    // ---------------- inversion path (1 block per batch, per XCD) ----------
    int b = blk;
    float* mcol = (float*)smem;        // [2][128]
    float* pivrow = (float*)smem + 256;  // [2][128]
    const float* Gp = Gpart + ((size_t)b * NSPLIT << 14);
    int cg = t & 15, rb = t >> 4;  // thread owns rows rb*8..+8, cols cg*8..+8
    float al = alpha[b], ga2 = 2.f * gamma[b];
    float a[8][8];
#pragma unroll
    for (int i = 0; i < 8; i++) {
      int r = rb * 8 + i;
      f32x4 s0 = (f32x4){0.f, 0.f, 0.f, 0.f}, s1 = s0;
#pragma unroll
      for (int ks = 0; ks < NSPLIT; ks++) {
        const float* base = Gp + ks * 16384 + r * 128 + cg * 8;
        s0 += *(const f32x4*)(base);
        s1 += *(const f32x4*)(base + 4);
      }
#pragma unroll
      for (int j = 0; j < 4; j++) {
        int c = cg * 8 + j;
        a[i][j] = ga2 * s0[j] + ((r == c) ? al : 0.f);
        a[i][4 + j] = ga2 * s1[j] + ((r == c + 4) ? 0.f : 0.f) + ((r == cg * 8 + 4 + j) ? al : 0.f);
      }
    }
    for (int p = 0; p < 128; ++p) {
      int pb = p & 1;
      int grp = p >> 3, sub = p & 7;
      if (cg == grp) {  // capture column p (pre-update, own regs)
#pragma unroll
        for (int i = 0; i < 8; i++) mcol[pb * 128 + rb * 8 + i] = sel8row(a[i], sub);
      }
      if (rb == grp) {  // capture row p (unnormalized)
        float col_k[8];
#pragma unroll
        for (int j = 0; j < 8; j++) {
#pragma unroll
          for (int i = 0; i < 8; i++) col_k[i] = a[i][j];
          pivrow[pb * 128 + cg * 8 + j] = sel8row(col_k, sub);
        }
      }
      __syncthreads();
      float invd = 1.0f / mcol[pb * 128 + p];
      f32x4 mc0 = *(const f32x4*)(mcol + pb * 128 + rb * 8);
      f32x4 mc1 = *(const f32x4*)(mcol + pb * 128 + rb * 8 + 4);
      f32x4 pr0 = *(const f32x4*)(pivrow + pb * 128 + cg * 8);
      f32x4 pr1 = *(const f32x4*)(pivrow + pb * 128 + cg * 8 + 4);
      float mc[8] = {mc0[0], mc0[1], mc0[2], mc0[3], mc1[0], mc1[1], mc1[2], mc1[3]};
      float pr[8] = {pr0[0], pr0[1], pr0[2], pr0[3], pr1[0], pr1[1], pr1[2], pr1[3]};
#pragma unroll
      for (int i = 0; i < 8; i++) {
        int r = rb * 8 + i;
        float mi = mc[i] * invd;
#pragma unroll
        for (int j = 0; j < 8; j++) {
          int c = cg * 8 + j;
          float v = a[i][j] - mi * pr[j];
          if (c == p) v = -mi;
          if (r == p) v = pr[j] * invd;
          if (r == p && c == p) v = invd;
          a[i][j] = v;
        }
      }
      // next capture writes the other parity buffer; no second barrier needed
    }
    float* dst = Cinv + ((size_t)b << 14);
#pragma unroll
    for (int i = 0; i < 8; i++) {
      int r = rb * 8 + i;
      *(f32x4*)(dst + r * 128 + cg * 8) = (f32x4){a[i][0], a[i][1], a[i][2], a[i][3]};
      *(f32x4*)(dst + r * 128 + cg * 8 + 4) = (f32x4){a[i][4], a[i][5], a[i][6], a[i][7]};
    }
    return;
  }
  // ---------------- AN GEMM path ------------------------------------------
  int b = blk & 7, mtile = (blk >> 3) - 1;
  const float* Ab = A + (size_t)b * 16777216 + (size_t)mtile * 64 * 4096;
  const unsigned short* Nb = Nbf + (size_t)b * 524288;
  int wave = t >> 6, lane = t & 63, quad = lane >> 4, l16 = lane & 15;
  int wm = wave >> 1, wr = wave & 1;
  f32x4 acc[2][4];
#pragma unroll
  for (int i = 0; i < 2; i++)
#pragma unroll
    for (int j = 0; j < 4; j++) acc[i][j] = (f32x4){0.f, 0.f, 0.f, 0.f};
  int arow = t >> 2, aq = t & 3;
  int brow = t >> 1, bhalf = t & 1;
  const float* asrc = Ab + (size_t)arow * 4096 + aq * 16;
  const unsigned short* bsrc = Nb + (size_t)brow * 4096 + bhalf * 32;
  unsigned short* adst_e = smem + arow * PAD + aq * 16;
  unsigned short* adst_o = adst_e + 64 * PAD;
  unsigned short* bdst_e = smem + 2 * 64 * PAD + brow * PAD + bhalf * 32;
  unsigned short* bdst_o = bdst_e + 128 * PAD;
  const unsigned short* lap_e = smem;
  const unsigned short* lap_o = smem + 64 * PAD;
  const unsigned short* lbp_e = smem + 2 * 64 * PAD;
  const unsigned short* lbp_o = lbp_e + 128 * PAD;
  // prologue: B(0), then A(0)->x, A(1)->y (B oldest -> counted waits stay counted)
  u32x4 B0 = *(const u32x4*)(bsrc + 0);
  u32x4 B1 = *(const u32x4*)(bsrc + 8);
  u32x4 B2 = *(const u32x4*)(bsrc + 16);
  u32x4 B3 = *(const u32x4*)(bsrc + 24);
  f32x4 xa0 = *(const f32x4*)(asrc + 0);
  f32x4 xa1 = *(const f32x4*)(asrc + 4);
  f32x4 xa2 = *(const f32x4*)(asrc + 8);
  f32x4 xa3 = *(const f32x4*)(asrc + 12);
  f32x4 ya0 = *(const f32x4*)(asrc + 64);
  f32x4 ya1 = *(const f32x4*)(asrc + 68);
  f32x4 ya2 = *(const f32x4*)(asrc + 72);
  f32x4 ya3 = *(const f32x4*)(asrc + 76);
  for (int m = 0; m < 32; ++m) {
    an_step(xa0, xa1, xa2, xa3, B0, B1, B2, B3, adst_e, bdst_e, lap_e, lbp_e,
            asrc, bsrc, 2 * m, wm, wr, quad, l16, acc);
    an_step(ya0, ya1, ya2, ya3, B0, B1, B2, B3, adst_o, bdst_o, lap_o, lbp_o,
            asrc, bsrc, 2 * m + 1, wm, wr, quad, l16, acc);
  }
  float* ob = ANf + (size_t)b * 524288 + (size_t)mtile * 64 * 128;
#pragma unroll
  for (int mt = 0; mt < 2; mt++)
#pragma unroll
    for (int rt = 0; rt < 4; rt++)
#pragma unroll
      for (int rg = 0; rg < 4; rg++) {
        int h = wm * 32 + mt * 16 + quad * 4 + rg;
        int r = wr * 64 + rt * 16 + l16;
        ob[h * 128 + r] = acc[mt][rt][rg];
      }
}

// ---------------------------------------------------------------------------
// Kernel 3: out[b][h][s] = 2g * sum_r AN[h][r] * Cinv[r][s]   (fp32 VALU)
// grid 512 (64 htiles x 8 b), 256 thr. Cinv fp32 in LDS (broadcast reads:
// sg = t>>4 -> 4 distinct LDS addresses/wave, conflict-free). AN from L2.
// ---------------------------------------------------------------------------
__global__ __launch_bounds__(256) void k_final(const float* __restrict__ AN,
                                               const float* __restrict__ Cinv,
                                               const float* __restrict__ gamma,
                                               float* __restrict__ out) {
  __attribute__((aligned(16))) __shared__ float Cs[16384];  // 64KB, [r][s]
  int blk = blockIdx.x;
  int b = blk & 7, mtile = blk >> 3;
  const float* Cb = Cinv + ((size_t)b << 14);
  int t = threadIdx.x;
#pragma unroll
  for (int c = 0; c < 4; c++) {
    int off = c * 4096 + t * 16;
#pragma unroll
    for (int q = 0; q < 4; q++)
      *(f32x4*)(Cs + off + q * 4) = *(const f32x4*)(Cb + off + q * 4);
  }
  __syncthreads();
  int sg = t >> 4, hg = t & 15;  // thread: 4 h-rows (hg*4..) x 8 s-cols (sg*8..)
  const float* ANb = AN + (size_t)b * 524288 + (size_t)mtile * 64 * 128;
  f32x4 acc[4][2];
#pragma unroll
  for (int i = 0; i < 4; i++) {
    acc[i][0] = (f32x4){0.f, 0.f, 0.f, 0.f};
    acc[i][1] = (f32x4){0.f, 0.f, 0.f, 0.f};
  }
  for (int r0 = 0; r0 < 128; r0 += 16) {
    f32x4 av[4][4];
#pragma unroll
    for (int i = 0; i < 4; i++)
#pragma unroll
      for (int k4 = 0; k4 < 4; k4++)
        av[i][k4] = *(const f32x4*)(ANb + (hg * 4 + i) * 128 + r0 + k4 * 4);
#pragma unroll
    for (int rr = 0; rr < 16; rr++) {
      f32x4 c0 = *(const f32x4*)(Cs + (r0 + rr) * 128 + sg * 8);
      f32x4 c1 = *(const f32x4*)(Cs + (r0 + rr) * 128 + sg * 8 + 4);
#pragma unroll
      for (int i = 0; i < 4; i++) {
        float aval = av[i][rr >> 2][rr & 3];
        acc[i][0] += aval * c0;
        acc[i][1] += aval * c1;
      }
    }
  }
  float ga2 = 2.f * gamma[b];
  float* ob = out + (size_t)b * 524288 + (size_t)mtile * 64 * 128;
#pragma unroll
  for (int i = 0; i < 4; i++) {
    *(f32x4*)(ob + (hg * 4 + i) * 128 + sg * 8) = ga2 * acc[i][0];
    *(f32x4*)(ob + (hg * 4 + i) * 128 + sg * 8 + 4) = ga2 * acc[i][1];
  }
}

// ---------------------------------------------------------------------------
extern "C" void kernel_launch(void* const* d_in, const int* in_sizes, int n_in,
                              void* d_out, int out_size, void* d_ws, size_t ws_size,
                              hipStream_t stream) {
  const float* N = (const float*)d_in[0];
  const float* Ak = (const float*)d_in[1];
  const float* alpha = (const float*)d_in[2];
  const float* gamma = (const float*)d_in[3];
  float* out = (float*)d_out;
  char* ws = (char*)d_ws;
  // workspace layout (~29.3 MB)
  unsigned short* Nbf = (unsigned short*)(ws);             // 8 MB : bf16(N)
  float* Gpart = (float*)(ws + 8388608);                   // 4 MB : gram partials
  float* Cinv = (float*)(ws + 12582912);                   // 512KB: fp32 inverses
  float* ANf = (float*)(ws + 13107200);                    // 16 MB: A@N^T fp32

  k_gram<<<dim3(NSPLIT, 8), 256, 0, stream>>>(N, Gpart, Nbf);
  k_aninv<<<dim3(520), 256, 0, stream>>>(Ak, Nbf, Gpart, alpha, gamma, ANf, Cinv);
  k_final<<<dim3(512), 256, 0, stream>>>(ANf, Cinv, gamma, out);
}

// Round 3
// 880.080 us; speedup vs baseline: 1.2480x; 1.2480x over previous
//
#include <hip/hip_runtime.h>

// ---------------------------------------------------------------------------
// Problem: B=8, R=128, H=W=4096
//   C    = alpha*I + 2*gamma * N @ N^T        [128x128], SPD -> Cinv symmetric
//   out  = 2*gamma * (Ak_L @ N^T) @ Cinv      (uses Cinv symmetry)
// Pipeline (4 launches, all components individually proven):
//   k_gram   : Gpart[b][ks] = partial N*N^T (bf16 MFMA) + writes Nbf = bf16(N)
//   k_inv    : C = alpha*I + 2g*sum(Gpart); 1024-thr in-place Gauss-Jordan
//              (4x4 per thread -> fits registers, no spill)
//   k_angemm : AN = A(fp32->bf16) @ Nbf^T  (512MB stream; round-1 v2 pipeline:
//              2-deep x/y register prefetch, LDS dbuf, raw s_barrier,
//              lgkmcnt(0)-only before barrier -> no vmcnt drain)
//   k_final  : out = 2g * AN @ Cinv, fp32 VALU (Cinv fp32 in LDS)
// ---------------------------------------------------------------------------

typedef __attribute__((ext_vector_type(8))) short bf16x8;
typedef __attribute__((ext_vector_type(4))) float f32x4;
typedef __attribute__((ext_vector_type(4))) unsigned int u32x4;

#define MFMA16(a, b, c) __builtin_amdgcn_mfma_f32_16x16x32_bf16((a), (b), (c), 0, 0, 0)
#define NSPLIT 8

__device__ __forceinline__ unsigned short f2bf(float f) {
  union { float f; unsigned u; } v; v.f = f;
  unsigned u = v.u;
  return (unsigned short)((u + 0x7FFFu + ((u >> 16) & 1u)) >> 16);  // RNE
}
__device__ __forceinline__ unsigned pack2(float x, float y) {
  return (unsigned)f2bf(x) | ((unsigned)f2bf(y) << 16);
}

// ---------------------------------------------------------------------------
// Kernel 1: Gram partials + Nbf cast. grid (NSPLIT=8, 8 batch), 256 thr.
// ---------------------------------------------------------------------------
__global__ __launch_bounds__(256) void k_gram(const float* __restrict__ N,
                                              float* __restrict__ Gpart,
                                              unsigned short* __restrict__ Nbf) {
  __attribute__((aligned(16))) __shared__ unsigned short lds[128 * 72];
  int ks = blockIdx.x, b = blockIdx.y;
  const float* Nb = N + (size_t)b * 524288 + ks * 512;
  int t = threadIdx.x;
  int wave = t >> 6, lane = t & 63, quad = lane >> 4, l16 = lane & 15;
  f32x4 acc[2][8];
#pragma unroll
  for (int i = 0; i < 2; i++)
#pragma unroll
    for (int j = 0; j < 8; j++) acc[i][j] = (f32x4){0.f, 0.f, 0.f, 0.f};
  int srow = t >> 1, shalf = t & 1;
  const float* srcb = Nb + (size_t)srow * 4096 + shalf * 32;
  unsigned short* dptr = lds + srow * 72 + shalf * 32;
  unsigned short* nbb = Nbf + (size_t)b * 524288 + (size_t)srow * 4096 + ks * 512 + shalf * 32;
  for (int it = 0; it < 8; ++it) {
    u32x4 pk0, pk1;
    {
      f32x4 v0 = *(const f32x4*)(srcb + it * 64 + 0);
      f32x4 v1 = *(const f32x4*)(srcb + it * 64 + 4);
      f32x4 v2 = *(const f32x4*)(srcb + it * 64 + 8);
      f32x4 v3 = *(const f32x4*)(srcb + it * 64 + 12);
      pk0[0] = pack2(v0[0], v0[1]); pk0[1] = pack2(v0[2], v0[3]);
      pk0[2] = pack2(v1[0], v1[1]); pk0[3] = pack2(v1[2], v1[3]);
      pk1[0] = pack2(v2[0], v2[1]); pk1[1] = pack2(v2[2], v2[3]);
      pk1[2] = pack2(v3[0], v3[1]); pk1[3] = pack2(v3[2], v3[3]);
    }
    u32x4 pk2, pk3;
    {
      f32x4 v0 = *(const f32x4*)(srcb + it * 64 + 16);
      f32x4 v1 = *(const f32x4*)(srcb + it * 64 + 20);
      f32x4 v2 = *(const f32x4*)(srcb + it * 64 + 24);
      f32x4 v3 = *(const f32x4*)(srcb + it * 64 + 28);
      pk2[0] = pack2(v0[0], v0[1]); pk2[1] = pack2(v0[2], v0[3]);
      pk2[2] = pack2(v1[0], v1[1]); pk2[3] = pack2(v1[2], v1[3]);
      pk3[0] = pack2(v2[0], v2[1]); pk3[1] = pack2(v2[2], v2[3]);
      pk3[2] = pack2(v3[0], v3[1]); pk3[3] = pack2(v3[2], v3[3]);
    }
    // bf16 copy of N (row-major), reused by k_angemm as the B operand
    *(u32x4*)(nbb + it * 64 + 0) = pk0;
    *(u32x4*)(nbb + it * 64 + 8) = pk1;
    *(u32x4*)(nbb + it * 64 + 16) = pk2;
    *(u32x4*)(nbb + it * 64 + 24) = pk3;
    __syncthreads();
    *(u32x4*)(dptr + 0) = pk0;
    *(u32x4*)(dptr + 8) = pk1;
    *(u32x4*)(dptr + 16) = pk2;
    *(u32x4*)(dptr + 24) = pk3;
    __syncthreads();
    bf16x8 af[2][2], bfv[8][2];
#pragma unroll
    for (int mt = 0; mt < 2; mt++)
#pragma unroll
      for (int kk = 0; kk < 2; kk++)
        af[mt][kk] = *(const bf16x8*)(lds + (wave * 32 + mt * 16 + l16) * 72 + (kk * 4 + quad) * 8);
#pragma unroll
    for (int nt = 0; nt < 8; nt++)
#pragma unroll
      for (int kk = 0; kk < 2; kk++)
        bfv[nt][kk] = *(const bf16x8*)(lds + (nt * 16 + l16) * 72 + (kk * 4 + quad) * 8);
#pragma unroll
    for (int mt = 0; mt < 2; mt++)
#pragma unroll
      for (int nt = 0; nt < 8; nt++)
#pragma unroll
        for (int kk = 0; kk < 2; kk++)
          acc[mt][nt] = MFMA16(af[mt][kk], bfv[nt][kk], acc[mt][nt]);
  }
  float* Gp = Gpart + ((size_t)(b * NSPLIT + ks) << 14);
#pragma unroll
  for (int mt = 0; mt < 2; mt++)
#pragma unroll
    for (int nt = 0; nt < 8; nt++)
#pragma unroll
      for (int rg = 0; rg < 4; rg++) {
        int row = wave * 32 + mt * 16 + quad * 4 + rg;
        int col = nt * 16 + l16;
        Gp[row * 128 + col] = acc[mt][nt][rg];
      }
}

// ---------------------------------------------------------------------------
// Kernel 2: in-place Gauss-Jordan inverse of C = alpha*I + 2g*sum(Gpart).
// grid (8), 1024 thr. Thread (rb=t>>5, cg=t&31) owns 4 rows x 4 cols.
// ONE barrier/step: capture col p + row p (pre-update, own regs) into
// parity-double-buffered LDS, barrier, rank-1 update. (proven round 0/1)
// ---------------------------------------------------------------------------
__global__ __launch_bounds__(1024) void k_inv(const float* __restrict__ Gpart,
                                              const float* __restrict__ alpha,
                                              const float* __restrict__ gamma,
                                              float* __restrict__ Cinv) {
  __attribute__((aligned(16))) __shared__ float Cs[16384];
  __attribute__((aligned(16))) __shared__ float mcol[2][128];
  __attribute__((aligned(16))) __shared__ float pivrow[2][128];
  int b = blockIdx.x;
  int t = threadIdx.x;
  const float* Gp = Gpart + ((size_t)b * NSPLIT << 14);
#pragma unroll
  for (int c = 0; c < 4; c++) {
    int off = c * 4096 + t * 4;
    f32x4 s = (f32x4){0.f, 0.f, 0.f, 0.f};
#pragma unroll
    for (int ks = 0; ks < NSPLIT; ks++) s += *(const f32x4*)(Gp + ks * 16384 + off);
    *(f32x4*)(Cs + off) = s;
  }
  __syncthreads();
  int cg = t & 31, rb = t >> 5;  // cg fastest -> coalesced epilogue
  float al = alpha[b], ga2 = 2.f * gamma[b];
  float a[4][4];
#pragma unroll
  for (int i = 0; i < 4; i++) {
    int r = rb * 4 + i;
    f32x4 v = *(const f32x4*)(Cs + r * 128 + cg * 4);
#pragma unroll
    for (int j = 0; j < 4; j++) {
      int c = cg * 4 + j;
      a[i][j] = ga2 * v[j] + ((r == c) ? al : 0.f);
    }
  }
  for (int p = 0; p < 128; ++p) {
    int pb = p & 1;
    int cgp = p >> 2, jp = p & 3;
    int rbp = p >> 2, ip = p & 3;
    if (cg == cgp) {  // capture column p (own regs, pre-update)
      f32x4 mv;
#pragma unroll
      for (int i = 0; i < 4; i++)
        mv[i] = (jp & 2) ? ((jp & 1) ? a[i][3] : a[i][2]) : ((jp & 1) ? a[i][1] : a[i][0]);
      *(f32x4*)&mcol[pb][rb * 4] = mv;
    }
    if (rb == rbp) {  // capture row p (unnormalized)
      f32x4 pv;
#pragma unroll
      for (int j = 0; j < 4; j++)
        pv[j] = (ip & 2) ? ((ip & 1) ? a[3][j] : a[2][j]) : ((ip & 1) ? a[1][j] : a[0][j]);
      *(f32x4*)&pivrow[pb][cg * 4] = pv;
    }
    __syncthreads();
    float invd = 1.0f / mcol[pb][p];  // mcol[p] == a[p][p]
    f32x4 mc = *(const f32x4*)&mcol[pb][rb * 4];
    f32x4 pr = *(const f32x4*)&pivrow[pb][cg * 4];
#pragma unroll
    for (int i = 0; i < 4; i++) {
      int r = rb * 4 + i;
      float mi = mc[i] * invd;
#pragma unroll
      for (int j = 0; j < 4; j++) {
        int c = cg * 4 + j;
        float v = a[i][j] - mi * pr[j];
        if (c == p) v = -mi;
        if (r == p) v = pr[j] * invd;
        if (r == p && c == p) v = invd;
        a[i][j] = v;
      }
    }
    // no second barrier: next capture writes the OTHER parity buffer and
    // reads only the capturing thread's own (in-order updated) registers.
  }
  float* dst = Cinv + ((size_t)b << 14);
#pragma unroll
  for (int i = 0; i < 4; i++) {
    int r = rb * 4 + i;
    *(f32x4*)(dst + r * 128 + cg * 4) = (f32x4){a[i][0], a[i][1], a[i][2], a[i][3]};
  }
}

// ---------------------------------------------------------------------------
// Kernel 3: AN[b][h][r] = sum_w A[b][h][w] * Nbf[b][r][w]
// grid 512 1D: b = blk&7 (XCD-swizzle), mtile = blk>>3. 256 thr (4 waves),
// tile 64(h) x 128(r), BK=64. Round-1 v2 pipeline verbatim:
// 2-deep register prefetch (sets x/y), double-buffered LDS,
// ONE raw s_barrier per K-iter (lgkmcnt(0)-only before it -> no vmcnt drain).
// ---------------------------------------------------------------------------
__device__ __forceinline__ void gemm_step(
    f32x4& A0, f32x4& A1, f32x4& A2, f32x4& A3,
    u32x4& B0, u32x4& B1, u32x4& B2, u32x4& B3,
    unsigned short* adst, unsigned short* bdst,
    const unsigned short* lap, const unsigned short* lbp,
    const float* asrc, const unsigned short* bsrc,
    int next_k0, int do_pf, int wm, int wr, int quad, int l16,
    f32x4 (&acc)[2][4]) {
  u32x4 pa0, pa1;  // pack A fp32->bf16 (the counted vmcnt wait lands here)
  pa0[0] = pack2(A0[0], A0[1]); pa0[1] = pack2(A0[2], A0[3]);
  pa0[2] = pack2(A1[0], A1[1]); pa0[3] = pack2(A1[2], A1[3]);
  pa1[0] = pack2(A2[0], A2[1]); pa1[1] = pack2(A2[2], A2[3]);
  pa1[2] = pack2(A3[0], A3[1]); pa1[3] = pack2(A3[2], A3[3]);
  *(u32x4*)(adst + 0) = pa0;
  *(u32x4*)(adst + 8) = pa1;
  *(u32x4*)(bdst + 0) = B0;
  *(u32x4*)(bdst + 8) = B1;
  *(u32x4*)(bdst + 16) = B2;
  *(u32x4*)(bdst + 24) = B3;
  asm volatile("s_waitcnt lgkmcnt(0)" ::: "memory");  // LDS visible; vmcnt untouched
  __builtin_amdgcn_s_barrier();
  __builtin_amdgcn_sched_barrier(0);
  if (do_pf) {  // refill this set for iter it+2 (uniform branch)
    A0 = *(const f32x4*)(asrc + next_k0 + 0);
    A1 = *(const f32x4*)(asrc + next_k0 + 4);
    A2 = *(const f32x4*)(asrc + next_k0 + 8);
    A3 = *(const f32x4*)(asrc + next_k0 + 12);
    B0 = *(const u32x4*)(bsrc + next_k0 + 0);
    B1 = *(const u32x4*)(bsrc + next_k0 + 8);
    B2 = *(const u32x4*)(bsrc + next_k0 + 16);
    B3 = *(const u32x4*)(bsrc + next_k0 + 24);
  }
  bf16x8 af[2][2], bfv[4][2];
#pragma unroll
  for (int mt = 0; mt < 2; mt++)
#pragma unroll
    for (int kk = 0; kk < 2; kk++)
      af[mt][kk] = *(const bf16x8*)(lap + (wm * 32 + mt * 16 + l16) * 72 + (kk * 4 + quad) * 8);
#pragma unroll
  for (int rt = 0; rt < 4; rt++)
#pragma unroll
    for (int kk = 0; kk < 2; kk++)
      bfv[rt][kk] = *(const bf16x8*)(lbp + (wr * 64 + rt * 16 + l16) * 72 + (kk * 4 + quad) * 8);
#pragma unroll
  for (int mt = 0; mt < 2; mt++)
#pragma unroll
    for (int rt = 0; rt < 4; rt++)
#pragma unroll
      for (int kk = 0; kk < 2; kk++)
        acc[mt][rt] = MFMA16(af[mt][kk], bfv[rt][kk], acc[mt][rt]);
}

__global__ __launch_bounds__(256) void k_angemm(const float* __restrict__ A,
                                                const unsigned short* __restrict__ Nbf,
                                                float* __restrict__ ANf) {
  __attribute__((aligned(16))) __shared__ unsigned short la[2][64 * 72];
  __attribute__((aligned(16))) __shared__ unsigned short lb[2][128 * 72];
  int blk = blockIdx.x;
  int b = blk & 7, mtile = blk >> 3;
  const float* Ab = A + (size_t)b * 16777216 + (size_t)mtile * 64 * 4096;
  const unsigned short* Mb = Nbf + (size_t)b * 524288;
  int t = threadIdx.x, wave = t >> 6, lane = t & 63, quad = lane >> 4, l16 = lane & 15;
  int wm = wave >> 1, wr = wave & 1;
  f32x4 acc[2][4];
#pragma unroll
  for (int i = 0; i < 2; i++)
#pragma unroll
    for (int j = 0; j < 4; j++) acc[i][j] = (f32x4){0.f, 0.f, 0.f, 0.f};
  int arow = t >> 2, aq = t & 3;
  int brow = t >> 1, bhalf = t & 1;
  const float* asrc = Ab + (size_t)arow * 4096 + aq * 16;
  const unsigned short* bsrc = Mb + (size_t)brow * 4096 + bhalf * 32;
  unsigned short* adst0 = &la[0][arow * 72 + aq * 16];
  unsigned short* adst1 = &la[1][arow * 72 + aq * 16];
  unsigned short* bdst0 = &lb[0][brow * 72 + bhalf * 32];
  unsigned short* bdst1 = &lb[1][brow * 72 + bhalf * 32];
  // prologue: issue iter 0 into set x, iter 1 into set y (16 loads in flight)
  f32x4 xa0 = *(const f32x4*)(asrc + 0);
  f32x4 xa1 = *(const f32x4*)(asrc + 4);
  f32x4 xa2 = *(const f32x4*)(asrc + 8);
  f32x4 xa3 = *(const f32x4*)(asrc + 12);
  u32x4 xb0 = *(const u32x4*)(bsrc + 0);
  u32x4 xb1 = *(const u32x4*)(bsrc + 8);
  u32x4 xb2 = *(const u32x4*)(bsrc + 16);
  u32x4 xb3 = *(const u32x4*)(bsrc + 24);
  f32x4 ya0 = *(const f32x4*)(asrc + 64);
  f32x4 ya1 = *(const f32x4*)(asrc + 68);
  f32x4 ya2 = *(const f32x4*)(asrc + 72);
  f32x4 ya3 = *(const f32x4*)(asrc + 76);
  u32x4 yb0 = *(const u32x4*)(bsrc + 64);
  u32x4 yb1 = *(const u32x4*)(bsrc + 72);
  u32x4 yb2 = *(const u32x4*)(bsrc + 80);
  u32x4 yb3 = *(const u32x4*)(bsrc + 88);
  for (int itp = 0; itp < 32; ++itp) {
    int pf = (itp < 31);
    gemm_step(xa0, xa1, xa2, xa3, xb0, xb1, xb2, xb3,
              adst0, bdst0, &la[0][0], &lb[0][0], asrc, bsrc,
              (2 * itp + 2) * 64, pf, wm, wr, quad, l16, acc);
    gemm_step(ya0, ya1, ya2, ya3, yb0, yb1, yb2, yb3,
              adst1, bdst1, &la[1][0], &lb[1][0], asrc, bsrc,
              (2 * itp + 3) * 64, pf, wm, wr, quad, l16, acc);
  }
  float* ob = ANf + (size_t)b * 524288 + (size_t)mtile * 64 * 128;
#pragma unroll
  for (int mt = 0; mt < 2; mt++)
#pragma unroll
    for (int rt = 0; rt < 4; rt++)
#pragma unroll
      for (int rg = 0; rg < 4; rg++) {
        int h = wm * 32 + mt * 16 + quad * 4 + rg;
        int r = wr * 64 + rt * 16 + l16;
        ob[h * 128 + r] = acc[mt][rt][rg];
      }
}

// ---------------------------------------------------------------------------
// Kernel 4: out[b][h][s] = 2g * sum_r AN[h][r] * Cinv[r][s]   (fp32 VALU)
// grid 512 (64 htiles x 8 b), 256 thr. Cinv fp32 in LDS.
// ---------------------------------------------------------------------------
__global__ __launch_bounds__(256) void k_final(const float* __restrict__ AN,
                                               const float* __restrict__ Cinv,
                                               const float* __restrict__ gamma,
                                               float* __restrict__ out) {
  __attribute__((aligned(16))) __shared__ float Cs[16384];  // 64KB, [r][s]
  int blk = blockIdx.x;
  int b = blk & 7, mtile = blk >> 3;
  const float* Cb = Cinv + ((size_t)b << 14);
  int t = threadIdx.x;
#pragma unroll
  for (int c = 0; c < 4; c++) {
    int off = c * 4096 + t * 16;
#pragma unroll
    for (int q = 0; q < 4; q++)
      *(f32x4*)(Cs + off + q * 4) = *(const f32x4*)(Cb + off + q * 4);
  }
  __syncthreads();
  int sg = t >> 4, hg = t & 15;  // thread: 4 h-rows (hg*4..) x 8 s-cols (sg*8..)
  const float* ANb = AN + (size_t)b * 524288 + (size_t)mtile * 64 * 128;
  f32x4 acc[4][2];
#pragma unroll
  for (int i = 0; i < 4; i++) {
    acc[i][0] = (f32x4){0.f, 0.f, 0.f, 0.f};
    acc[i][1] = (f32x4){0.f, 0.f, 0.f, 0.f};
  }
  for (int r0 = 0; r0 < 128; r0 += 16) {
    f32x4 av[4][4];
#pragma unroll
    for (int i = 0; i < 4; i++)
#pragma unroll
      for (int k4 = 0; k4 < 4; k4++)
        av[i][k4] = *(const f32x4*)(ANb + (hg * 4 + i) * 128 + r0 + k4 * 4);
#pragma unroll
    for (int rr = 0; rr < 16; rr++) {
      f32x4 c0 = *(const f32x4*)(Cs + (r0 + rr) * 128 + sg * 8);
      f32x4 c1 = *(const f32x4*)(Cs + (r0 + rr) * 128 + sg * 8 + 4);
#pragma unroll
      for (int i = 0; i < 4; i++) {
        float aval = av[i][rr >> 2][rr & 3];
        acc[i][0] += aval * c0;
        acc[i][1] += aval * c1;
      }
    }
  }
  float ga2 = 2.f * gamma[b];
  float* ob = out + (size_t)b * 524288 + (size_t)mtile * 64 * 128;
#pragma unroll
  for (int i = 0; i < 4; i++) {
    *(f32x4*)(ob + (hg * 4 + i) * 128 + sg * 8) = ga2 * acc[i][0];
    *(f32x4*)(ob + (hg * 4 + i) * 128 + sg * 8 + 4) = ga2 * acc[i][1];
  }
}

// ---------------------------------------------------------------------------
extern "C" void kernel_launch(void* const* d_in, const int* in_sizes, int n_in,
                              void* d_out, int out_size, void* d_ws, size_t ws_size,
                              hipStream_t stream) {
  const float* N = (const float*)d_in[0];
  const float* Ak = (const float*)d_in[1];
  const float* alpha = (const float*)d_in[2];
  const float* gamma = (const float*)d_in[3];
  float* out = (float*)d_out;
  char* ws = (char*)d_ws;
  // workspace layout (~28.5 MB)
  unsigned short* Nbf = (unsigned short*)(ws);             // 8 MB : bf16(N)
  float* Gpart = (float*)(ws + 8388608);                   // 4 MB : gram partials
  float* Cinv = (float*)(ws + 12582912);                   // 512KB: fp32 inverses
  float* ANf = (float*)(ws + 13107200);                    // 16 MB: A@N^T fp32

  k_gram<<<dim3(NSPLIT, 8), 256, 0, stream>>>(N, Gpart, Nbf);
  k_inv<<<dim3(8), 1024, 0, stream>>>(Gpart, alpha, gamma, Cinv);
  k_angemm<<<dim3(512), 256, 0, stream>>>(Ak, Nbf, ANf);
  k_final<<<dim3(512), 256, 0, stream>>>(ANf, Cinv, gamma, out);
}